// Round 8
// baseline (205.735 us; speedup 1.0000x reference)
//
#include <hip/hip_runtime.h>
#include <hip/hip_bf16.h>

#define NB 2
#define NN 8192
#define NC 256
#define NH 8
#define NCH 2048

static constexpr float EPS = 1e-5f;

// ---------------------------------------------------------------------------
// Factorization (per batch b, head h):
//   G = emb^T emb                        [256x256]  (Et staging, tri tiles, split-K)
//   T1[hd][c] = sum_c' Wq[c'][hd] G[c][c']
//   attn[d][e] = sum_c T1[hd][c] Wk[c][he]          (+ variance stats)
//   SM = softmax(attn * rsqrt(var+eps))             (mean shift cancels)
//   M[c][d] = sum_e Wv[c][he] SM[d][e]
//   P[j][c] += sum_d Wor[h][j][d] M[c][d]           (fp32 atomics over h)
//   out[n][j] = sum_c emb[n][c] P[j][c]             (fp32-split A and B on the fly)
// All GEMM operands bf16 hi/lo pairs: x = hi + lo; acc += hi*hi + hi*lo + lo*hi.
// Rules learned: (r4,r6) >=1024-block grids or >=4 blocks/CU — no mega-fusion;
// (r7) tiny L2-resident GEMMs want wave-per-tile direct loads, not LDS staging.
// ---------------------------------------------------------------------------

typedef __attribute__((ext_vector_type(8))) short bf16x8;
typedef __attribute__((ext_vector_type(4))) float f32x4;

#define MFMA16(a, b, c) __builtin_amdgcn_mfma_f32_16x16x32_bf16(a, b, c, 0, 0, 0)

// ---- ws layout -------------------------------------------------------------
// float region:
//   Gp   [2][16][10][4096] @ 0        (1,310,720) gram split-K tri partials
//   attn [16][256][256]    @ 0        (alias; Gp dead after k_s2)
//   P    [2][256][256]     @ 1310720  (131,072) fp32, atomic target
//   stats[64]              @ 1441792
// ushort region at float offset 1441856:
static constexpr int ETH  = 0;         // Et hi [2][256][8192]
static constexpr int ETL  = 4194304;
static constexpr int WQTH = 8388608;   // Wq^T hi [2048][256]
static constexpr int WQTL = 8912896;
static constexpr int WKTH = 9437184;
static constexpr int WKTL = 9961472;
static constexpr int WVH  = 10485760;  // Wv hi [256][2048]
static constexpr int WVL  = 11010048;
static constexpr int WORH = 11534336;  // Wor hi [8][256][256]: Wor[h][j][d] = Wo[d*8+h][j]
static constexpr int WORL = 12058624;
static constexpr int GHH  = 12582912;  // G hi [2][256][256]
static constexpr int GHL  = 12713984;
static constexpr int T1H  = 12845056;  // T1 hi [2][2048][256]; reused as M [16][256][256]
static constexpr int T1L  = 13893632;
static constexpr int SMH  = 14942208;  // softmax hi [16][256][256]
static constexpr int SML  = 15990784;

// ---- helpers ---------------------------------------------------------------

__device__ __forceinline__ ushort bf16rn(float x) {
    uint u = __float_as_uint(x);
    return (ushort)((u + 0x7fffu + ((u >> 16) & 1u)) >> 16);
}
__device__ __forceinline__ float bf2f(ushort h) { return __uint_as_float(((uint)h) << 16); }

// stage a 64x64 bf16 tile (k-contiguous source) into XOR-swizzled LDS (256 thr).
__device__ __forceinline__ void stage64(ushort* __restrict__ lds, const ushort* __restrict__ src,
                                        int row0, int k0, int ld) {
    int t = threadIdx.x;
    int g = t & 7, r = t >> 3;
#pragma unroll
    for (int i = 0; i < 2; ++i, r += 32) {
        uint4 v = *(const uint4*)(src + (row0 + r) * ld + k0 + g * 8);
        *(uint4*)((char*)lds + r * 128 + ((g ^ (r & 7)) << 4)) = v;
    }
}

// stage 64x64 from fp32 source with on-the-fly hi/lo split (256 thr)
__device__ __forceinline__ void stage64_f32(ushort* __restrict__ ldsh, ushort* __restrict__ ldsl,
                                            const float* __restrict__ src, int row0, int k0, int ld) {
    int t = threadIdx.x;
    int g = t & 15, r = t >> 4;
#pragma unroll
    for (int i = 0; i < 4; ++i, r += 16) {
        float4 v = *(const float4*)(src + (row0 + r) * ld + k0 + g * 4);
        ushort h0 = bf16rn(v.x), h1 = bf16rn(v.y), h2 = bf16rn(v.z), h3 = bf16rn(v.w);
        ushort e0 = bf16rn(v.x - bf2f(h0)), e1 = bf16rn(v.y - bf2f(h1));
        ushort e2 = bf16rn(v.z - bf2f(h2)), e3 = bf16rn(v.w - bf2f(h3));
        int byte = r * 128 + ((((g >> 1) ^ (r & 7)) << 4) | ((g & 1) << 3));
        ushort4 hv = {h0, h1, h2, h3}, lv = {e0, e1, e2, e3};
        *(ushort4*)((char*)ldsh + byte) = hv;
        *(ushort4*)((char*)ldsl + byte) = lv;
    }
}

// LDS fragment: lane holds row rbase+(l&15), 8 bf16 at k = ks*32+(l>>4)*8
__device__ __forceinline__ bf16x8 frag64(const ushort* __restrict__ lds, int rbase, int ks) {
    int l = threadIdx.x & 63;
    int r = rbase + (l & 15);
    int slot = (ks * 4 + (l >> 4)) ^ (r & 7);
    return *(const bf16x8*)((const char*)lds + r * 128 + slot * 16);
}

// direct-global fragment, same lane layout (L2-resident operands)
__device__ __forceinline__ bf16x8 gfrag(const ushort* __restrict__ src, int row0, int ld, int k) {
    int l = threadIdx.x & 63;
    return *(const bf16x8*)(src + (row0 + (l & 15)) * ld + k + (l >> 4) * 8);
}

__device__ __forceinline__ void mac3(f32x4& acc, bf16x8 ah, bf16x8 al, bf16x8 bh, bf16x8 bl) {
    acc = MFMA16(ah, bh, acc);
    acc = MFMA16(ah, bl, acc);
    acc = MFMA16(al, bh, acc);
}

// wave-per-tile 16x16 TN GEMM: out[m][n] = sum_k A[arow0+m][k0a+k]*B[brow0+n][k0b+k]
template <int NK>
__device__ __forceinline__ f32x4 wave_gemm(const ushort* __restrict__ Ah, const ushort* __restrict__ Al,
                                           int arow0, int lda, int k0a,
                                           const ushort* __restrict__ Bh, const ushort* __restrict__ Bl,
                                           int brow0, int ldb, int k0b) {
    f32x4 acc = {0.f, 0.f, 0.f, 0.f};
#pragma unroll
    for (int ks = 0; ks < NK; ++ks) {
        bf16x8 ah = gfrag(Ah, arow0, lda, k0a + ks * 32);
        bf16x8 al = gfrag(Al, arow0, lda, k0a + ks * 32);
        bf16x8 bh = gfrag(Bh, brow0, ldb, k0b + ks * 32);
        bf16x8 bl = gfrag(Bl, brow0, ldb, k0b + ks * 32);
        mac3(acc, ah, al, bh, bl);
    }
    return acc;
}

// 4-wave 64x64 mfma over one staged k-tile (256-thr kernels)
__device__ __forceinline__ void mfma_tile(const ushort* Ah, const ushort* Al,
                                          const ushort* Bh, const ushort* Bl,
                                          int wm, int wn, f32x4 acc[2][2]) {
#pragma unroll
    for (int ks = 0; ks < 2; ++ks) {
        bf16x8 ah[2], al[2], bh[2], bl[2];
        ah[0] = frag64(Ah, wm, ks);      ah[1] = frag64(Ah, wm + 16, ks);
        al[0] = frag64(Al, wm, ks);      al[1] = frag64(Al, wm + 16, ks);
        bh[0] = frag64(Bh, wn, ks);      bh[1] = frag64(Bh, wn + 16, ks);
        bl[0] = frag64(Bl, wn, ks);      bl[1] = frag64(Bl, wn + 16, ks);
#pragma unroll
        for (int mi = 0; mi < 2; ++mi)
#pragma unroll
            for (int ni = 0; ni < 2; ++ni)
                mac3(acc[mi][ni], ah[mi], al[mi], bh[ni], bl[ni]);
    }
}

__device__ __forceinline__ void ep_f32(float* D, int ld, int row0, int col0, f32x4 acc[2][2]) {
    int l = threadIdx.x & 63, w = threadIdx.x >> 6;
    int wm = (w >> 1) * 32, wn = (w & 1) * 32;
#pragma unroll
    for (int mi = 0; mi < 2; ++mi)
#pragma unroll
        for (int ni = 0; ni < 2; ++ni)
#pragma unroll
            for (int r = 0; r < 4; ++r)
                D[(row0 + wm + mi * 16 + (l >> 4) * 4 + r) * ld + col0 + wn + ni * 16 + (l & 15)] = acc[mi][ni][r];
}

// transpose+split a 64x64 fp32 tile: src[m*srcStride + j] -> dst[j*NC + m] (hi/lo)
__device__ __forceinline__ void tsplit(uint (*lds)[65], const float* __restrict__ src, int srcStride,
                                       ushort* __restrict__ DH, ushort* __restrict__ DL) {
    int t = threadIdx.x;
    int r = t >> 4, g = t & 15;
#pragma unroll
    for (int i = 0; i < 4; ++i) {
        int m = r + i * 16;
        float4 v = *(const float4*)(src + m * srcStride + g * 4);
        ushort h;
        h = bf16rn(v.x); lds[g * 4 + 0][m] = h | ((uint)bf16rn(v.x - bf2f(h)) << 16);
        h = bf16rn(v.y); lds[g * 4 + 1][m] = h | ((uint)bf16rn(v.y - bf2f(h)) << 16);
        h = bf16rn(v.z); lds[g * 4 + 2][m] = h | ((uint)bf16rn(v.z - bf2f(h)) << 16);
        h = bf16rn(v.w); lds[g * 4 + 3][m] = h | ((uint)bf16rn(v.w - bf2f(h)) << 16);
    }
    __syncthreads();
    int j = t >> 3, q = t & 7;
#pragma unroll
    for (int i = 0; i < 2; ++i) {
        int jj = j + i * 32;
        uint a0 = lds[jj][q * 8 + 0], a1 = lds[jj][q * 8 + 1], a2 = lds[jj][q * 8 + 2], a3 = lds[jj][q * 8 + 3];
        uint a4 = lds[jj][q * 8 + 4], a5 = lds[jj][q * 8 + 5], a6 = lds[jj][q * 8 + 6], a7 = lds[jj][q * 8 + 7];
        uint4 hv = {(a0 & 0xffffu) | (a1 << 16), (a2 & 0xffffu) | (a3 << 16),
                    (a4 & 0xffffu) | (a5 << 16), (a6 & 0xffffu) | (a7 << 16)};
        uint4 lv = {(a0 >> 16) | (a1 & 0xffff0000u), (a2 >> 16) | (a3 & 0xffff0000u),
                    (a4 >> 16) | (a5 & 0xffff0000u), (a6 >> 16) | (a7 & 0xffff0000u)};
        *(uint4*)(DH + jj * NC + q * 8) = hv;
        *(uint4*)(DL + jj * NC + q * 8) = lv;
    }
}

// ---- kernels ---------------------------------------------------------------

// merged prep + emb transpose. grid (512, 6):
//  y=0 Wq^T, y=1 Wk^T (x<128); y=2 Wo rearrange (x<128);
//  y=3 Wv split + zero stats + zero P (x<512); y=4,5 emb->Et for b=y-4 (x<512)
__global__ __launch_bounds__(256) void k_prep(const float* __restrict__ wq, const float* __restrict__ wk,
                                              const float* __restrict__ wv, const float* __restrict__ wo,
                                              const float* __restrict__ emb, ushort* __restrict__ us,
                                              float* __restrict__ P, float* __restrict__ stats) {
    __shared__ uint lds[64][65];
    int x = blockIdx.x, z = blockIdx.y;
    int t = threadIdx.x;
    if (z >= 4) {
        // emb -> Et hi/lo [b][c][n]
        int b = z - 4, nt = x >> 2, ct = x & 3;
        const float* E = emb + b * (NN * NC);
        int n0 = nt * 64, c0 = ct * 64;
        int r = t >> 4, g = t & 15;
#pragma unroll
        for (int i = 0; i < 4; ++i) {
            int n = r + i * 16;
            float4 v = *(const float4*)(E + (n0 + n) * NC + c0 + g * 4);
            ushort h;
            h = bf16rn(v.x); lds[g * 4 + 0][n] = h | ((uint)bf16rn(v.x - bf2f(h)) << 16);
            h = bf16rn(v.y); lds[g * 4 + 1][n] = h | ((uint)bf16rn(v.y - bf2f(h)) << 16);
            h = bf16rn(v.z); lds[g * 4 + 2][n] = h | ((uint)bf16rn(v.z - bf2f(h)) << 16);
            h = bf16rn(v.w); lds[g * 4 + 3][n] = h | ((uint)bf16rn(v.w - bf2f(h)) << 16);
        }
        __syncthreads();
        ushort* EH = us + ETH + b * (NC * NN);
        ushort* EL = us + ETL + b * (NC * NN);
        int c = t >> 3, q = t & 7;
#pragma unroll
        for (int i = 0; i < 2; ++i) {
            int cc = c + i * 32;
            uint a0 = lds[cc][q * 8 + 0], a1 = lds[cc][q * 8 + 1], a2 = lds[cc][q * 8 + 2], a3 = lds[cc][q * 8 + 3];
            uint a4 = lds[cc][q * 8 + 4], a5 = lds[cc][q * 8 + 5], a6 = lds[cc][q * 8 + 6], a7 = lds[cc][q * 8 + 7];
            uint4 hv = {(a0 & 0xffffu) | (a1 << 16), (a2 & 0xffffu) | (a3 << 16),
                        (a4 & 0xffffu) | (a5 << 16), (a6 & 0xffffu) | (a7 << 16)};
            uint4 lv = {(a0 >> 16) | (a1 & 0xffff0000u), (a2 >> 16) | (a3 & 0xffff0000u),
                        (a4 >> 16) | (a5 & 0xffff0000u), (a6 >> 16) | (a7 & 0xffff0000u)};
            *(uint4*)(EH + (c0 + cc) * NN + n0 + q * 8) = hv;
            *(uint4*)(EL + (c0 + cc) * NN + n0 + q * 8) = lv;
        }
        return;
    }
    if (z == 3) {
        if (x == 0 && t < 64) stats[t] = 0.f;
        P[x * 256 + t] = 0.f;   // zero P [2][256][256] = 131072 = 512*256
        int i = (x * 256 + t) * 4;
        float4 v = *(const float4*)(wv + i);
        ushort h0 = bf16rn(v.x), h1 = bf16rn(v.y), h2 = bf16rn(v.z), h3 = bf16rn(v.w);
        ushort e0 = bf16rn(v.x - bf2f(h0)), e1 = bf16rn(v.y - bf2f(h1));
        ushort e2 = bf16rn(v.z - bf2f(h2)), e3 = bf16rn(v.w - bf2f(h3));
        ushort4 hv = {h0, h1, h2, h3}, lv = {e0, e1, e2, e3};
        *(ushort4*)(us + WVH + i) = hv;
        *(ushort4*)(us + WVL + i) = lv;
        return;
    }
    if (x >= 128) return;
    if (z == 2) {
        int h = x >> 4, dt = (x >> 2) & 3, jt = x & 3;
        tsplit(lds, wo + (dt * 64 * 8 + h) * NC + jt * 64, 8 * NC,
               us + WORH + h * 65536 + (jt * 64) * NC + dt * 64,
               us + WORL + h * 65536 + (jt * 64) * NC + dt * 64);
        return;
    }
    int jt = x >> 2, ct = x & 3;
    const float* W = z ? wk : wq;
    int dh = (z ? WKTH : WQTH) + (jt * 64) * NC + ct * 64;
    int dl = (z ? WKTL : WQTL) + (jt * 64) * NC + ct * 64;
    tsplit(lds, W + (ct * 64) * NCH + jt * 64, NCH, us + dh, us + dl);
}

static __device__ const int TI1[10] = {0, 0, 0, 0, 1, 1, 1, 2, 2, 3};
static __device__ const int TI2[10] = {0, 1, 2, 3, 1, 2, 3, 2, 3, 3};

// gram split-K partials over Et, triangular tiles. grid (10, 16, 2)
__global__ __launch_bounds__(256) void k_gram(const ushort* __restrict__ us, float* __restrict__ gp) {
    __shared__ ushort lds[16384];
    ushort* Ah = lds; ushort* Al = lds + 4096; ushort* Bh = lds + 8192; ushort* Bl = lds + 12288;
    int tile = blockIdx.x, kc = blockIdx.y, b = blockIdx.z;
    int c1 = TI1[tile] * 64, c2 = TI2[tile] * 64;
    bool diag = (c1 == c2);
    const ushort* eh = us + ETH + b * (NC * NN);
    const ushort* el = us + ETL + b * (NC * NN);
    int w = threadIdx.x >> 6;
    int wm = (w >> 1) * 32, wn = (w & 1) * 32;
    f32x4 acc[2][2] = {{{0.f, 0.f, 0.f, 0.f}, {0.f, 0.f, 0.f, 0.f}},
                       {{0.f, 0.f, 0.f, 0.f}, {0.f, 0.f, 0.f, 0.f}}};
    for (int kb = 0; kb < 8; ++kb) {
        int n0 = kc * 512 + kb * 64;
        stage64(Ah, eh, c1, n0, NN);
        stage64(Al, el, c1, n0, NN);
        if (!diag) { stage64(Bh, eh, c2, n0, NN); stage64(Bl, el, c2, n0, NN); }
        __syncthreads();
        mfma_tile(Ah, Al, diag ? Ah : Bh, diag ? Al : Bl, wm, wn, acc);
        __syncthreads();
    }
    ep_f32(gp + ((b * 16 + kc) * 10 + tile) * 4096, 64, 0, 0, acc);
}

// reduce 16 gram partials per tri tile, split -> G hi/lo, mirror off-diag. grid (10, 2)
__global__ __launch_bounds__(256) void k_s2(const float* __restrict__ gp, ushort* __restrict__ us) {
    __shared__ float T[64][65];
    int tile = blockIdx.x, b = blockIdx.y;
    int c1 = TI1[tile] * 64, c2 = TI2[tile] * 64;
    int t = threadIdx.x;
    const float* src = gp + (b * 160 + tile) * 4096;
    ushort* GH = us + GHH + b * 65536;
    ushort* GL = us + GHL + b * 65536;
    float4 s[4] = {{0.f, 0.f, 0.f, 0.f}, {0.f, 0.f, 0.f, 0.f}, {0.f, 0.f, 0.f, 0.f}, {0.f, 0.f, 0.f, 0.f}};
    for (int kc = 0; kc < 16; ++kc) {
        const float4* p = (const float4*)(src + kc * 40960);
#pragma unroll
        for (int k2 = 0; k2 < 4; ++k2) {
            float4 v = p[t + k2 * 256];
            s[k2].x += v.x; s[k2].y += v.y; s[k2].z += v.z; s[k2].w += v.w;
        }
    }
#pragma unroll
    for (int k2 = 0; k2 < 4; ++k2) {
        int f = t + k2 * 256;
        int r = f >> 4, c = (f & 15) * 4;
        ushort h0 = bf16rn(s[k2].x), h1 = bf16rn(s[k2].y), h2 = bf16rn(s[k2].z), h3 = bf16rn(s[k2].w);
        ushort e0 = bf16rn(s[k2].x - bf2f(h0)), e1 = bf16rn(s[k2].y - bf2f(h1));
        ushort e2 = bf16rn(s[k2].z - bf2f(h2)), e3 = bf16rn(s[k2].w - bf2f(h3));
        ushort4 hv = {h0, h1, h2, h3}, lv = {e0, e1, e2, e3};
        *(ushort4*)(GH + (c1 + r) * NC + c2 + c) = hv;
        *(ushort4*)(GL + (c1 + r) * NC + c2 + c) = lv;
        T[r][c + 0] = s[k2].x; T[r][c + 1] = s[k2].y; T[r][c + 2] = s[k2].z; T[r][c + 3] = s[k2].w;
    }
    if (c1 != c2) {
        __syncthreads();
#pragma unroll
        for (int k2 = 0; k2 < 4; ++k2) {
            int f = t + k2 * 256;
            int r = f >> 4, c = (f & 15) * 4;
            float a0 = T[c + 0][r], a1 = T[c + 1][r], a2 = T[c + 2][r], a3 = T[c + 3][r];
            ushort h0 = bf16rn(a0), h1 = bf16rn(a1), h2 = bf16rn(a2), h3 = bf16rn(a3);
            ushort e0 = bf16rn(a0 - bf2f(h0)), e1 = bf16rn(a1 - bf2f(h1));
            ushort e2 = bf16rn(a2 - bf2f(h2)), e3 = bf16rn(a3 - bf2f(h3));
            ushort4 hv = {h0, h1, h2, h3}, lv = {e0, e1, e2, e3};
            *(ushort4*)(GH + (c2 + r) * NC + c1 + c) = hv;
            *(ushort4*)(GL + (c2 + r) * NC + c1 + c) = lv;
        }
    }
}

// T1 = Wq^T G, wave-per-16x16-tile. grid 1024 x 256 thr (4096 waves)
__global__ __launch_bounds__(256) void k_t1w(ushort* __restrict__ us) {
    int wid = blockIdx.x * 4 + (threadIdx.x >> 6);
    int b = wid >> 11, rem = wid & 2047;
    int rt = rem >> 4, ct = rem & 15;
    f32x4 acc = wave_gemm<8>(us + WQTH, us + WQTL, rt * 16, NC, 0,
                             us + GHH + b * 65536, us + GHL + b * 65536, ct * 16, NC, 0);
    int l = threadIdx.x & 63;
    ushort* Dh = us + T1H + b * 524288;
    ushort* Dl = us + T1L + b * 524288;
#pragma unroll
    for (int r = 0; r < 4; ++r) {
        float x = acc[r];
        int idx = (rt * 16 + (l >> 4) * 4 + r) * NC + ct * 16 + (l & 15);
        ushort h = bf16rn(x);
        Dh[idx] = h;
        Dl[idx] = bf16rn(x - bf2f(h));
    }
}

// attn = T1 @ Wk + stats, wave-per-tile. grid 1024 (4 waves/block share bh)
__global__ __launch_bounds__(256) void k_attnw(const ushort* __restrict__ us, float* __restrict__ attn,
                                               float* __restrict__ stats) {
    __shared__ float red[8];
    int w = threadIdx.x >> 6, l = threadIdx.x & 63;
    int bh = blockIdx.x >> 6;
    int tile = (blockIdx.x & 63) * 4 + w;
    int dt = tile >> 4, et = tile & 15;
    int b = bh >> 3, h = bh & 7;
    f32x4 acc = wave_gemm<8>(us + T1H + b * 524288, us + T1L + b * 524288, h * 256 + dt * 16, NC, 0,
                             us + WKTH, us + WKTL, h * 256 + et * 16, NC, 0);
    float* D = attn + bh * 65536;
    float s = 0.f, ss = 0.f;
#pragma unroll
    for (int r = 0; r < 4; ++r) {
        float x = acc[r];
        D[(dt * 16 + (l >> 4) * 4 + r) * NC + et * 16 + (l & 15)] = x;
        s += x; ss += x * x;
    }
#pragma unroll
    for (int o = 32; o > 0; o >>= 1) { s += __shfl_xor(s, o); ss += __shfl_xor(ss, o); }
    if (l == 0) { red[w] = s; red[4 + w] = ss; }
    __syncthreads();
    if (threadIdx.x == 0) {
        atomicAdd(&stats[bh * 2], red[0] + red[1] + red[2] + red[3]);
        atomicAdd(&stats[bh * 2 + 1], red[4] + red[5] + red[6] + red[7]);
    }
}

// fused instnorm-scale + softmax, write hi/lo. grid (16 bh, 16 rb)
__global__ __launch_bounds__(256) void k_sm(const float* __restrict__ attn, const float* __restrict__ stats,
                                            ushort* __restrict__ us) {
    int bh = blockIdx.x, rb = blockIdx.y;
    float mean = stats[bh * 2] * (1.f / 65536.f);
    float var = stats[bh * 2 + 1] * (1.f / 65536.f) - mean * mean;
    float rs = rsqrtf(var + EPS);
    int w = threadIdx.x >> 6, l = threadIdx.x & 63;
    const float* src = attn + bh * 65536;
    ushort* dh = us + SMH + bh * 65536;
    ushort* dl = us + SML + bh * 65536;
#pragma unroll
    for (int rr = 0; rr < 4; ++rr) {
        int row = rb * 16 + w * 4 + rr;
        float4 v = *(const float4*)(src + row * 256 + l * 4);
        v.x *= rs; v.y *= rs; v.z *= rs; v.w *= rs;
        float mx = fmaxf(fmaxf(v.x, v.y), fmaxf(v.z, v.w));
#pragma unroll
        for (int o = 32; o > 0; o >>= 1) mx = fmaxf(mx, __shfl_xor(mx, o));
        float e0 = __expf(v.x - mx), e1 = __expf(v.y - mx), e2 = __expf(v.z - mx), e3 = __expf(v.w - mx);
        float se = e0 + e1 + e2 + e3;
#pragma unroll
        for (int o = 32; o > 0; o >>= 1) se += __shfl_xor(se, o);
        float inv = 1.f / se;
        e0 *= inv; e1 *= inv; e2 *= inv; e3 *= inv;
        ushort h0 = bf16rn(e0), h1 = bf16rn(e1), h2 = bf16rn(e2), h3 = bf16rn(e3);
        ushort f0 = bf16rn(e0 - bf2f(h0)), f1 = bf16rn(e1 - bf2f(h1));
        ushort f2 = bf16rn(e2 - bf2f(h2)), f3 = bf16rn(e3 - bf2f(h3));
        ushort4 hv = {h0, h1, h2, h3}, lv = {f0, f1, f2, f3};
        *(ushort4*)(dh + row * 256 + l * 4) = hv;
        *(ushort4*)(dl + row * 256 + l * 4) = lv;
    }
}

// M[c][d] = sum_e Wv[c][he] SM[d][e], wave-per-tile. grid 1024. M overwrites T1.
__global__ __launch_bounds__(256) void k_mw(ushort* __restrict__ us) {
    int wid = blockIdx.x * 4 + (threadIdx.x >> 6);
    int bh = wid >> 8, rem = wid & 255;
    int ct = rem >> 4, dt = rem & 15;
    int h = bh & 7;
    f32x4 acc = wave_gemm<8>(us + WVH, us + WVL, ct * 16, NCH, h * 256,
                             us + SMH + bh * 65536, us + SML + bh * 65536, dt * 16, NC, 0);
    int l = threadIdx.x & 63;
    ushort* Dh = us + T1H + bh * 65536;
    ushort* Dl = us + T1L + bh * 65536;
#pragma unroll
    for (int r = 0; r < 4; ++r) {
        float x = acc[r];
        int idx = (ct * 16 + (l >> 4) * 4 + r) * NC + dt * 16 + (l & 15);
        ushort hh = bf16rn(x);
        Dh[idx] = hh;
        Dl[idx] = bf16rn(x - bf2f(hh));
    }
}

// P[b][j][c] += sum_d Wor[h][j][d] M[bh][c][d], wave-per-tile + fp32 atomics. grid 1024
__global__ __launch_bounds__(256) void k_ptw(const ushort* __restrict__ us, float* __restrict__ P) {
    int wid = blockIdx.x * 4 + (threadIdx.x >> 6);
    int bh = wid >> 8, rem = wid & 255;
    int jt = rem >> 4, ct = rem & 15;
    int b = bh >> 3, h = bh & 7;
    f32x4 acc = wave_gemm<8>(us + WORH + h * 65536, us + WORL + h * 65536, jt * 16, NC, 0,
                             us + T1H + bh * 65536, us + T1L + bh * 65536, ct * 16, NC, 0);
    int l = threadIdx.x & 63;
    float* D = P + b * 65536;
#pragma unroll
    for (int r = 0; r < 4; ++r)
        atomicAdd(&D[(jt * 16 + (l >> 4) * 4 + r) * NC + ct * 16 + (l & 15)], acc[r]);
}

// out = emb @ P^T. grid (128 nt, 4 jt, 2 b). A and B split on the fly from fp32.
__global__ __launch_bounds__(256) void k_out(const float* __restrict__ emb, const float* __restrict__ P,
                                             float* __restrict__ out) {
    __shared__ ushort lds[16384];
    ushort* Ah = lds; ushort* Al = lds + 4096; ushort* Bh = lds + 8192; ushort* Bl = lds + 12288;
    int nt = blockIdx.x, jt = blockIdx.y, b = blockIdx.z;
    const float* E = emb + b * (NN * NC);
    const float* Pb = P + b * 65536;
    int w = threadIdx.x >> 6;
    int wm = (w >> 1) * 32, wn = (w & 1) * 32;
    f32x4 acc[2][2] = {{{0.f, 0.f, 0.f, 0.f}, {0.f, 0.f, 0.f, 0.f}},
                       {{0.f, 0.f, 0.f, 0.f}, {0.f, 0.f, 0.f, 0.f}}};
    for (int t = 0; t < 4; ++t) {
        stage64_f32(Ah, Al, E, nt * 64, t * 64, NC);
        stage64_f32(Bh, Bl, Pb, jt * 64, t * 64, NC);
        __syncthreads();
        mfma_tile(Ah, Al, Bh, Bl, wm, wn, acc);
        __syncthreads();
    }
    ep_f32(out + b * (NN * NC), NC, nt * 64, jt * 64, acc);
}

// ---------------------------------------------------------------------------

extern "C" void kernel_launch(void* const* d_in, const int* in_sizes, int n_in,
                              void* d_out, int out_size, void* d_ws, size_t ws_size,
                              hipStream_t stream) {
    const float* emb = (const float*)d_in[0];
    const float* Wq  = (const float*)d_in[1];
    const float* Wk  = (const float*)d_in[2];
    const float* Wv  = (const float*)d_in[3];
    const float* Wo  = (const float*)d_in[4];
    float* out = (float*)d_out;
    float* ws  = (float*)d_ws;

    float* Gp    = ws;                 // [2][16][10][4096]
    float* attn  = ws;                 // alias (Gp dead after k_s2)
    float* P     = ws + 1310720;       // [2][256][256] fp32
    float* stats = ws + 1441792;       // 64 floats
    ushort* us   = (ushort*)(ws + 1441856);

    k_prep <<<dim3(512, 6),     dim3(256), 0, stream>>>(Wq, Wk, Wv, Wo, emb, us, P, stats);
    k_gram <<<dim3(10, 16, NB), dim3(256), 0, stream>>>(us, Gp);
    k_s2   <<<dim3(10, NB),     dim3(256), 0, stream>>>(Gp, us);
    k_t1w  <<<dim3(1024),       dim3(256), 0, stream>>>(us);
    k_attnw<<<dim3(1024),       dim3(256), 0, stream>>>(us, attn, stats);
    k_sm   <<<dim3(16, 16),     dim3(256), 0, stream>>>(attn, stats, us);
    k_mw   <<<dim3(1024),       dim3(256), 0, stream>>>(us);
    k_ptw  <<<dim3(1024),       dim3(256), 0, stream>>>(us, P);
    k_out  <<<dim3(128, 4, NB), dim3(256), 0, stream>>>(emb, P, out);
}

// Round 9
// 165.687 us; speedup vs baseline: 1.2417x; 1.2417x over previous
//
#include <hip/hip_runtime.h>
#include <hip/hip_bf16.h>

#define NB 2
#define NN 8192
#define NC 256
#define NH 8
#define NCH 2048

static constexpr float EPS = 1e-5f;

// ---------------------------------------------------------------------------
// Factorization (per batch b, head h):
//   G = emb^T emb                        [256x256]  (Et staging, tri tiles, split-K 32)
//   T1[hd][c] = sum_c' Wq[c'][hd] G[c][c']
//   attn[d][e] = sum_c T1[hd][c] Wk[c][he]          (+ variance stats)
//   SM = softmax(attn * rsqrt(var+eps))             (mean shift cancels)
//   M[c][d] = sum_e Wv[c][he] SM[d][e]
//   P[j][c] += sum_d Wor[h][j][d] M[c][d]           (fp32 atomics over h)
//   out[n][j] = sum_c emb[n][c] P[j][c]             (fp32-split A and B on the fly)
// All GEMM operands bf16 hi/lo pairs: x = hi + lo; acc += hi*hi + hi*lo + lo*hi.
// Rules learned: (r4,r6) no mega-fusion — keep >=4 blocks/CU or >=1024 blocks;
// (r8) keep LDS staging — direct-global wave fragments are 4x transactions, no reuse.
// ---------------------------------------------------------------------------

typedef __attribute__((ext_vector_type(8))) short bf16x8;
typedef __attribute__((ext_vector_type(4))) float f32x4;

#define MFMA16(a, b, c) __builtin_amdgcn_mfma_f32_16x16x32_bf16(a, b, c, 0, 0, 0)

// ---- ws layout -------------------------------------------------------------
// float region:
//   Gp   [2][32][10][4096] @ 0        (2,621,440) gram split-K tri partials
//   attn [16][256][256]    @ 0        (alias; Gp dead after k_s2)
//   P    [2][256][256]     @ 2621440  fp32 atomic target
//   stats[64]              @ 2752512
// ushort region at float offset 2752576:
static constexpr int ETH  = 0;         // Et hi [2][256][8192]
static constexpr int ETL  = 4194304;
static constexpr int WQTH = 8388608;   // Wq^T hi [2048][256]
static constexpr int WQTL = 8912896;
static constexpr int WKTH = 9437184;
static constexpr int WKTL = 9961472;
static constexpr int WVH  = 10485760;  // Wv hi [256][2048]
static constexpr int WVL  = 11010048;
static constexpr int WORH = 11534336;  // Wor hi [8][256][256]: Wor[h][j][d] = Wo[d*8+h][j]
static constexpr int WORL = 12058624;
static constexpr int GHH  = 12582912;  // G hi [2][256][256]
static constexpr int GHL  = 12713984;
static constexpr int T1H  = 12845056;  // T1 hi [2][2048][256]; reused as M [16][256][256]
static constexpr int T1L  = 13893632;
static constexpr int SMH  = 14942208;  // softmax hi [16][256][256]
static constexpr int SML  = 15990784;

// ---- helpers ---------------------------------------------------------------

__device__ __forceinline__ ushort bf16rn(float x) {
    uint u = __float_as_uint(x);
    return (ushort)((u + 0x7fffu + ((u >> 16) & 1u)) >> 16);
}
__device__ __forceinline__ float bf2f(ushort h) { return __uint_as_float(((uint)h) << 16); }

// stage a 64x64 bf16 tile (k-contiguous source) into XOR-swizzled LDS (256 thr).
__device__ __forceinline__ void stage64(ushort* __restrict__ lds, const ushort* __restrict__ src,
                                        int row0, int k0, int ld) {
    int t = threadIdx.x;
    int g = t & 7, r = t >> 3;
#pragma unroll
    for (int i = 0; i < 2; ++i, r += 32) {
        uint4 v = *(const uint4*)(src + (row0 + r) * ld + k0 + g * 8);
        *(uint4*)((char*)lds + r * 128 + ((g ^ (r & 7)) << 4)) = v;
    }
}

// stage 64x64 from fp32 source with on-the-fly hi/lo split (256 thr)
__device__ __forceinline__ void stage64_f32(ushort* __restrict__ ldsh, ushort* __restrict__ ldsl,
                                            const float* __restrict__ src, int row0, int k0, int ld) {
    int t = threadIdx.x;
    int g = t & 15, r = t >> 4;
#pragma unroll
    for (int i = 0; i < 4; ++i, r += 16) {
        float4 v = *(const float4*)(src + (row0 + r) * ld + k0 + g * 4);
        ushort h0 = bf16rn(v.x), h1 = bf16rn(v.y), h2 = bf16rn(v.z), h3 = bf16rn(v.w);
        ushort e0 = bf16rn(v.x - bf2f(h0)), e1 = bf16rn(v.y - bf2f(h1));
        ushort e2 = bf16rn(v.z - bf2f(h2)), e3 = bf16rn(v.w - bf2f(h3));
        int byte = r * 128 + ((((g >> 1) ^ (r & 7)) << 4) | ((g & 1) << 3));
        ushort4 hv = {h0, h1, h2, h3}, lv = {e0, e1, e2, e3};
        *(ushort4*)((char*)ldsh + byte) = hv;
        *(ushort4*)((char*)ldsl + byte) = lv;
    }
}

// read one A/B fragment: lane holds row rbase+(l&15), 8 bf16 at k = ks*32+(l>>4)*8
__device__ __forceinline__ bf16x8 frag64(const ushort* __restrict__ lds, int rbase, int ks) {
    int l = threadIdx.x & 63;
    int r = rbase + (l & 15);
    int slot = (ks * 4 + (l >> 4)) ^ (r & 7);
    return *(const bf16x8*)((const char*)lds + r * 128 + slot * 16);
}

__device__ __forceinline__ void mac3(f32x4& acc, bf16x8 ah, bf16x8 al, bf16x8 bh, bf16x8 bl) {
    acc = MFMA16(ah, bh, acc);
    acc = MFMA16(ah, bl, acc);
    acc = MFMA16(al, bh, acc);
}

// 4-wave 64x64 mfma over one staged k-tile (256-thr kernels)
__device__ __forceinline__ void mfma_tile(const ushort* Ah, const ushort* Al,
                                          const ushort* Bh, const ushort* Bl,
                                          int wm, int wn, f32x4 acc[2][2]) {
#pragma unroll
    for (int ks = 0; ks < 2; ++ks) {
        bf16x8 ah[2], al[2], bh[2], bl[2];
        ah[0] = frag64(Ah, wm, ks);      ah[1] = frag64(Ah, wm + 16, ks);
        al[0] = frag64(Al, wm, ks);      al[1] = frag64(Al, wm + 16, ks);
        bh[0] = frag64(Bh, wn, ks);      bh[1] = frag64(Bh, wn + 16, ks);
        bl[0] = frag64(Bl, wn, ks);      bl[1] = frag64(Bl, wn + 16, ks);
#pragma unroll
        for (int mi = 0; mi < 2; ++mi)
#pragma unroll
            for (int ni = 0; ni < 2; ++ni)
                mac3(acc[mi][ni], ah[mi], al[mi], bh[ni], bl[ni]);
    }
}

// full TN GEMM over nkt 64-wide k-tiles; 4 waves, 64x64 output tile, 32 KB LDS
__device__ __forceinline__ void gemm_core(const ushort* Ahi, const ushort* Alo, int arow0, int lda, int k0a,
                                          const ushort* Bhi, const ushort* Blo, int brow0, int ldb, int k0b,
                                          int nkt, ushort* lds, f32x4 acc[2][2]) {
    ushort* Ah = lds; ushort* Al = lds + 4096; ushort* Bh = lds + 8192; ushort* Bl = lds + 12288;
    int w = threadIdx.x >> 6;
    int wm = (w >> 1) * 32, wn = (w & 1) * 32;
    for (int t = 0; t < nkt; ++t) {
        stage64(Ah, Ahi, arow0, k0a + t * 64, lda);
        stage64(Al, Alo, arow0, k0a + t * 64, lda);
        stage64(Bh, Bhi, brow0, k0b + t * 64, ldb);
        stage64(Bl, Blo, brow0, k0b + t * 64, ldb);
        __syncthreads();
        mfma_tile(Ah, Al, Bh, Bl, wm, wn, acc);
        __syncthreads();
    }
}

__device__ __forceinline__ void ep_hilo(ushort* Dh, ushort* Dl, int ld, int row0, int col0, f32x4 acc[2][2]) {
    int l = threadIdx.x & 63, w = threadIdx.x >> 6;
    int wm = (w >> 1) * 32, wn = (w & 1) * 32;
#pragma unroll
    for (int mi = 0; mi < 2; ++mi)
#pragma unroll
        for (int ni = 0; ni < 2; ++ni)
#pragma unroll
            for (int r = 0; r < 4; ++r) {
                float x = acc[mi][ni][r];
                int idx = (row0 + wm + mi * 16 + (l >> 4) * 4 + r) * ld + col0 + wn + ni * 16 + (l & 15);
                ushort h = bf16rn(x);
                Dh[idx] = h;
                Dl[idx] = bf16rn(x - bf2f(h));
            }
}

__device__ __forceinline__ void ep_f32(float* D, int ld, int row0, int col0, f32x4 acc[2][2]) {
    int l = threadIdx.x & 63, w = threadIdx.x >> 6;
    int wm = (w >> 1) * 32, wn = (w & 1) * 32;
#pragma unroll
    for (int mi = 0; mi < 2; ++mi)
#pragma unroll
        for (int ni = 0; ni < 2; ++ni)
#pragma unroll
            for (int r = 0; r < 4; ++r)
                D[(row0 + wm + mi * 16 + (l >> 4) * 4 + r) * ld + col0 + wn + ni * 16 + (l & 15)] = acc[mi][ni][r];
}

// transpose+split a 64x64 fp32 tile: src[m*srcStride + j] -> dst[j*NC + m] (hi/lo)
__device__ __forceinline__ void tsplit(uint (*lds)[65], const float* __restrict__ src, int srcStride,
                                       ushort* __restrict__ DH, ushort* __restrict__ DL) {
    int t = threadIdx.x;
    int r = t >> 4, g = t & 15;
#pragma unroll
    for (int i = 0; i < 4; ++i) {
        int m = r + i * 16;
        float4 v = *(const float4*)(src + m * srcStride + g * 4);
        ushort h;
        h = bf16rn(v.x); lds[g * 4 + 0][m] = h | ((uint)bf16rn(v.x - bf2f(h)) << 16);
        h = bf16rn(v.y); lds[g * 4 + 1][m] = h | ((uint)bf16rn(v.y - bf2f(h)) << 16);
        h = bf16rn(v.z); lds[g * 4 + 2][m] = h | ((uint)bf16rn(v.z - bf2f(h)) << 16);
        h = bf16rn(v.w); lds[g * 4 + 3][m] = h | ((uint)bf16rn(v.w - bf2f(h)) << 16);
    }
    __syncthreads();
    int j = t >> 3, q = t & 7;
#pragma unroll
    for (int i = 0; i < 2; ++i) {
        int jj = j + i * 32;
        uint a0 = lds[jj][q * 8 + 0], a1 = lds[jj][q * 8 + 1], a2 = lds[jj][q * 8 + 2], a3 = lds[jj][q * 8 + 3];
        uint a4 = lds[jj][q * 8 + 4], a5 = lds[jj][q * 8 + 5], a6 = lds[jj][q * 8 + 6], a7 = lds[jj][q * 8 + 7];
        uint4 hv = {(a0 & 0xffffu) | (a1 << 16), (a2 & 0xffffu) | (a3 << 16),
                    (a4 & 0xffffu) | (a5 << 16), (a6 & 0xffffu) | (a7 << 16)};
        uint4 lv = {(a0 >> 16) | (a1 & 0xffff0000u), (a2 >> 16) | (a3 & 0xffff0000u),
                    (a4 >> 16) | (a5 & 0xffff0000u), (a6 >> 16) | (a7 & 0xffff0000u)};
        *(uint4*)(DH + jj * NC + q * 8) = hv;
        *(uint4*)(DL + jj * NC + q * 8) = lv;
    }
}

// ---- kernels ---------------------------------------------------------------

// merged prep + emb transpose. grid (512, 6):
//  z=0 Wq^T, z=1 Wk^T (x<128); z=2 Wo rearrange (x<128);
//  z=3 Wv split + zero stats + zero P (x<512); z=4,5 emb->Et for b=z-4 (x<512)
__global__ __launch_bounds__(256) void k_prep(const float* __restrict__ wq, const float* __restrict__ wk,
                                              const float* __restrict__ wv, const float* __restrict__ wo,
                                              const float* __restrict__ emb, ushort* __restrict__ us,
                                              float* __restrict__ P, float* __restrict__ stats) {
    __shared__ uint lds[64][65];
    int x = blockIdx.x, z = blockIdx.y;
    int t = threadIdx.x;
    if (z >= 4) {
        int b = z - 4, nt = x >> 2, ct = x & 3;
        const float* E = emb + b * (NN * NC);
        int n0 = nt * 64, c0 = ct * 64;
        int r = t >> 4, g = t & 15;
#pragma unroll
        for (int i = 0; i < 4; ++i) {
            int n = r + i * 16;
            float4 v = *(const float4*)(E + (n0 + n) * NC + c0 + g * 4);
            ushort h;
            h = bf16rn(v.x); lds[g * 4 + 0][n] = h | ((uint)bf16rn(v.x - bf2f(h)) << 16);
            h = bf16rn(v.y); lds[g * 4 + 1][n] = h | ((uint)bf16rn(v.y - bf2f(h)) << 16);
            h = bf16rn(v.z); lds[g * 4 + 2][n] = h | ((uint)bf16rn(v.z - bf2f(h)) << 16);
            h = bf16rn(v.w); lds[g * 4 + 3][n] = h | ((uint)bf16rn(v.w - bf2f(h)) << 16);
        }
        __syncthreads();
        ushort* EH = us + ETH + b * (NC * NN);
        ushort* EL = us + ETL + b * (NC * NN);
        int c = t >> 3, q = t & 7;
#pragma unroll
        for (int i = 0; i < 2; ++i) {
            int cc = c + i * 32;
            uint a0 = lds[cc][q * 8 + 0], a1 = lds[cc][q * 8 + 1], a2 = lds[cc][q * 8 + 2], a3 = lds[cc][q * 8 + 3];
            uint a4 = lds[cc][q * 8 + 4], a5 = lds[cc][q * 8 + 5], a6 = lds[cc][q * 8 + 6], a7 = lds[cc][q * 8 + 7];
            uint4 hv = {(a0 & 0xffffu) | (a1 << 16), (a2 & 0xffffu) | (a3 << 16),
                        (a4 & 0xffffu) | (a5 << 16), (a6 & 0xffffu) | (a7 << 16)};
            uint4 lv = {(a0 >> 16) | (a1 & 0xffff0000u), (a2 >> 16) | (a3 & 0xffff0000u),
                        (a4 >> 16) | (a5 & 0xffff0000u), (a6 >> 16) | (a7 & 0xffff0000u)};
            *(uint4*)(EH + (c0 + cc) * NN + n0 + q * 8) = hv;
            *(uint4*)(EL + (c0 + cc) * NN + n0 + q * 8) = lv;
        }
        return;
    }
    if (z == 3) {
        if (x == 0 && t < 64) stats[t] = 0.f;
        P[x * 256 + t] = 0.f;  // 512*256 = 131072 floats
        int i = (x * 256 + t) * 4;
        float4 v = *(const float4*)(wv + i);
        ushort h0 = bf16rn(v.x), h1 = bf16rn(v.y), h2 = bf16rn(v.z), h3 = bf16rn(v.w);
        ushort e0 = bf16rn(v.x - bf2f(h0)), e1 = bf16rn(v.y - bf2f(h1));
        ushort e2 = bf16rn(v.z - bf2f(h2)), e3 = bf16rn(v.w - bf2f(h3));
        ushort4 hv = {h0, h1, h2, h3}, lv = {e0, e1, e2, e3};
        *(ushort4*)(us + WVH + i) = hv;
        *(ushort4*)(us + WVL + i) = lv;
        return;
    }
    if (x >= 128) return;
    if (z == 2) {
        int h = x >> 4, dt = (x >> 2) & 3, jt = x & 3;
        tsplit(lds, wo + (dt * 64 * 8 + h) * NC + jt * 64, 8 * NC,
               us + WORH + h * 65536 + (jt * 64) * NC + dt * 64,
               us + WORL + h * 65536 + (jt * 64) * NC + dt * 64);
        return;
    }
    int jt = x >> 2, ct = x & 3;
    const float* W = z ? wk : wq;
    int dh = (z ? WKTH : WQTH) + (jt * 64) * NC + ct * 64;
    int dl = (z ? WKTL : WQTL) + (jt * 64) * NC + ct * 64;
    tsplit(lds, W + (ct * 64) * NCH + jt * 64, NCH, us + dh, us + dl);
}

static __device__ const int TI1[10] = {0, 0, 0, 0, 1, 1, 1, 2, 2, 3};
static __device__ const int TI2[10] = {0, 1, 2, 3, 1, 2, 3, 2, 3, 3};

// gram split-K partials over Et, triangular tiles. grid (10, 32, 2)
__global__ __launch_bounds__(256) void k_gram(const ushort* __restrict__ us, float* __restrict__ gp) {
    __shared__ ushort lds[16384];
    ushort* Ah = lds; ushort* Al = lds + 4096; ushort* Bh = lds + 8192; ushort* Bl = lds + 12288;
    int tile = blockIdx.x, kc = blockIdx.y, b = blockIdx.z;
    int c1 = TI1[tile] * 64, c2 = TI2[tile] * 64;
    bool diag = (c1 == c2);
    const ushort* eh = us + ETH + b * (NC * NN);
    const ushort* el = us + ETL + b * (NC * NN);
    int w = threadIdx.x >> 6;
    int wm = (w >> 1) * 32, wn = (w & 1) * 32;
    f32x4 acc[2][2] = {{{0.f, 0.f, 0.f, 0.f}, {0.f, 0.f, 0.f, 0.f}},
                       {{0.f, 0.f, 0.f, 0.f}, {0.f, 0.f, 0.f, 0.f}}};
    for (int kb = 0; kb < 4; ++kb) {
        int n0 = kc * 256 + kb * 64;
        stage64(Ah, eh, c1, n0, NN);
        stage64(Al, el, c1, n0, NN);
        if (!diag) { stage64(Bh, eh, c2, n0, NN); stage64(Bl, el, c2, n0, NN); }
        __syncthreads();
        mfma_tile(Ah, Al, diag ? Ah : Bh, diag ? Al : Bl, wm, wn, acc);
        __syncthreads();
    }
    ep_f32(gp + ((b * 32 + kc) * 10 + tile) * 4096, 64, 0, 0, acc);
}

// reduce 32 gram partials per tri tile, split -> G hi/lo, mirror off-diag. grid (10, 2)
__global__ __launch_bounds__(256) void k_s2(const float* __restrict__ gp, ushort* __restrict__ us) {
    __shared__ float T[64][65];
    int tile = blockIdx.x, b = blockIdx.y;
    int c1 = TI1[tile] * 64, c2 = TI2[tile] * 64;
    int t = threadIdx.x;
    const float* src = gp + (b * 320 + tile) * 4096;
    ushort* GH = us + GHH + b * 65536;
    ushort* GL = us + GHL + b * 65536;
    float4 s[4] = {{0.f, 0.f, 0.f, 0.f}, {0.f, 0.f, 0.f, 0.f}, {0.f, 0.f, 0.f, 0.f}, {0.f, 0.f, 0.f, 0.f}};
    for (int kc = 0; kc < 32; ++kc) {
        const float4* p = (const float4*)(src + kc * 40960);
#pragma unroll
        for (int k2 = 0; k2 < 4; ++k2) {
            float4 v = p[t + k2 * 256];
            s[k2].x += v.x; s[k2].y += v.y; s[k2].z += v.z; s[k2].w += v.w;
        }
    }
#pragma unroll
    for (int k2 = 0; k2 < 4; ++k2) {
        int f = t + k2 * 256;
        int r = f >> 4, c = (f & 15) * 4;
        ushort h0 = bf16rn(s[k2].x), h1 = bf16rn(s[k2].y), h2 = bf16rn(s[k2].z), h3 = bf16rn(s[k2].w);
        ushort e0 = bf16rn(s[k2].x - bf2f(h0)), e1 = bf16rn(s[k2].y - bf2f(h1));
        ushort e2 = bf16rn(s[k2].z - bf2f(h2)), e3 = bf16rn(s[k2].w - bf2f(h3));
        ushort4 hv = {h0, h1, h2, h3}, lv = {e0, e1, e2, e3};
        *(ushort4*)(GH + (c1 + r) * NC + c2 + c) = hv;
        *(ushort4*)(GL + (c1 + r) * NC + c2 + c) = lv;
        T[r][c + 0] = s[k2].x; T[r][c + 1] = s[k2].y; T[r][c + 2] = s[k2].z; T[r][c + 3] = s[k2].w;
    }
    if (c1 != c2) {
        __syncthreads();
#pragma unroll
        for (int k2 = 0; k2 < 4; ++k2) {
            int f = t + k2 * 256;
            int r = f >> 4, c = (f & 15) * 4;
            float a0 = T[c + 0][r], a1 = T[c + 1][r], a2 = T[c + 2][r], a3 = T[c + 3][r];
            ushort h0 = bf16rn(a0), h1 = bf16rn(a1), h2 = bf16rn(a2), h3 = bf16rn(a3);
            ushort e0 = bf16rn(a0 - bf2f(h0)), e1 = bf16rn(a1 - bf2f(h1));
            ushort e2 = bf16rn(a2 - bf2f(h2)), e3 = bf16rn(a3 - bf2f(h3));
            ushort4 hv = {h0, h1, h2, h3}, lv = {e0, e1, e2, e3};
            *(uint4*)(GH + (c2 + r) * NC + c1 + c) = *(uint4*)&hv;
            *(uint4*)(GL + (c2 + r) * NC + c1 + c) = *(uint4*)&lv;
        }
    }
}

// T1 = Wq^T G. grid (32 mt, 4 nt, 2 b)
__global__ __launch_bounds__(256) void k_t1(ushort* __restrict__ us) {
    __shared__ ushort lds[16384];
    int mt = blockIdx.x, nt = blockIdx.y, b = blockIdx.z;
    f32x4 acc[2][2] = {{{0.f, 0.f, 0.f, 0.f}, {0.f, 0.f, 0.f, 0.f}},
                       {{0.f, 0.f, 0.f, 0.f}, {0.f, 0.f, 0.f, 0.f}}};
    gemm_core(us + WQTH, us + WQTL, mt * 64, NC, 0,
              us + GHH + b * 65536, us + GHL + b * 65536, nt * 64, NC, 0, 4, lds, acc);
    ep_hilo(us + T1H + b * 524288, us + T1L + b * 524288, NC, mt * 64, nt * 64, acc);
}

// attn = T1 @ Wk (per head) + variance stats. grid (16 tiles, 16 bh)
__global__ __launch_bounds__(256) void k_attn(ushort* __restrict__ us, float* __restrict__ attn,
                                              float* __restrict__ stats) {
    __shared__ ushort lds[16384];
    int tile = blockIdx.x, bh = blockIdx.y;
    int b = bh >> 3, h = bh & 7;
    int row0 = (tile >> 2) * 64, col0 = (tile & 3) * 64;
    f32x4 acc[2][2] = {{{0.f, 0.f, 0.f, 0.f}, {0.f, 0.f, 0.f, 0.f}},
                       {{0.f, 0.f, 0.f, 0.f}, {0.f, 0.f, 0.f, 0.f}}};
    gemm_core(us + T1H + b * 524288, us + T1L + b * 524288, h * 256 + row0, NC, 0,
              us + WKTH, us + WKTL, h * 256 + col0, NC, 0, 4, lds, acc);
    float* D = attn + bh * 65536;
    int l = threadIdx.x & 63, w = threadIdx.x >> 6;
    int wm = (w >> 1) * 32, wn = (w & 1) * 32;
    float lsum = 0.f, lss = 0.f;
#pragma unroll
    for (int mi = 0; mi < 2; ++mi)
#pragma unroll
        for (int ni = 0; ni < 2; ++ni)
#pragma unroll
            for (int r = 0; r < 4; ++r) {
                float x = acc[mi][ni][r];
                D[(row0 + wm + mi * 16 + (l >> 4) * 4 + r) * NC + col0 + wn + ni * 16 + (l & 15)] = x;
                lsum += x; lss += x * x;
            }
#pragma unroll
    for (int o = 32; o > 0; o >>= 1) { lsum += __shfl_xor(lsum, o); lss += __shfl_xor(lss, o); }
    if (l == 0) { atomicAdd(&stats[bh * 2], lsum); atomicAdd(&stats[bh * 2 + 1], lss); }
}

// fused instnorm-scale + softmax, write hi/lo. grid (16 bh, 16 rb)
__global__ __launch_bounds__(256) void k_sm(const float* __restrict__ attn, const float* __restrict__ stats,
                                            ushort* __restrict__ us) {
    int bh = blockIdx.x, rb = blockIdx.y;
    float mean = stats[bh * 2] * (1.f / 65536.f);
    float var = stats[bh * 2 + 1] * (1.f / 65536.f) - mean * mean;
    float rs = rsqrtf(var + EPS);
    int w = threadIdx.x >> 6, l = threadIdx.x & 63;
    const float* src = attn + bh * 65536;
    ushort* dh = us + SMH + bh * 65536;
    ushort* dl = us + SML + bh * 65536;
#pragma unroll
    for (int rr = 0; rr < 4; ++rr) {
        int row = rb * 16 + w * 4 + rr;
        float4 v = *(const float4*)(src + row * 256 + l * 4);
        v.x *= rs; v.y *= rs; v.z *= rs; v.w *= rs;
        float mx = fmaxf(fmaxf(v.x, v.y), fmaxf(v.z, v.w));
#pragma unroll
        for (int o = 32; o > 0; o >>= 1) mx = fmaxf(mx, __shfl_xor(mx, o));
        float e0 = __expf(v.x - mx), e1 = __expf(v.y - mx), e2 = __expf(v.z - mx), e3 = __expf(v.w - mx);
        float se = e0 + e1 + e2 + e3;
#pragma unroll
        for (int o = 32; o > 0; o >>= 1) se += __shfl_xor(se, o);
        float inv = 1.f / se;
        e0 *= inv; e1 *= inv; e2 *= inv; e3 *= inv;
        ushort h0 = bf16rn(e0), h1 = bf16rn(e1), h2 = bf16rn(e2), h3 = bf16rn(e3);
        ushort f0 = bf16rn(e0 - bf2f(h0)), f1 = bf16rn(e1 - bf2f(h1));
        ushort f2 = bf16rn(e2 - bf2f(h2)), f3 = bf16rn(e3 - bf2f(h3));
        ushort4 hv = {h0, h1, h2, h3}, lv = {f0, f1, f2, f3};
        *(ushort4*)(dh + row * 256 + l * 4) = hv;
        *(ushort4*)(dl + row * 256 + l * 4) = lv;
    }
}

// M[c][d] = sum_e Wv[c][h*256+e] SM[d][e]. grid (16 tiles, 16 bh). M overwrites T1.
__global__ __launch_bounds__(256) void k_m(ushort* __restrict__ us) {
    __shared__ ushort lds[16384];
    int tile = blockIdx.x, bh = blockIdx.y;
    int h = bh & 7;
    int c0 = (tile >> 2) * 64, d0 = (tile & 3) * 64;
    f32x4 acc[2][2] = {{{0.f, 0.f, 0.f, 0.f}, {0.f, 0.f, 0.f, 0.f}},
                       {{0.f, 0.f, 0.f, 0.f}, {0.f, 0.f, 0.f, 0.f}}};
    gemm_core(us + WVH, us + WVL, c0, NCH, h * 256,
              us + SMH + bh * 65536, us + SML + bh * 65536, d0, NC, 0, 4, lds, acc);
    ep_hilo(us + T1H + bh * 65536, us + T1L + bh * 65536, NC, c0, d0, acc);
}

// P[b][j][c] += sum_d Wor[h][j][d] M[bh][c][d], fp32 atomics. grid (16 tiles, 16 bh)
__global__ __launch_bounds__(256) void k_pt(ushort* __restrict__ us, float* __restrict__ P) {
    __shared__ ushort lds[16384];
    int tile = blockIdx.x, bh = blockIdx.y;
    int b = bh >> 3, h = bh & 7;
    int j0 = (tile >> 2) * 64, c0 = (tile & 3) * 64;
    f32x4 acc[2][2] = {{{0.f, 0.f, 0.f, 0.f}, {0.f, 0.f, 0.f, 0.f}},
                       {{0.f, 0.f, 0.f, 0.f}, {0.f, 0.f, 0.f, 0.f}}};
    gemm_core(us + WORH + h * 65536, us + WORL + h * 65536, j0, NC, 0,
              us + T1H + bh * 65536, us + T1L + bh * 65536, c0, NC, 0, 4, lds, acc);
    float* D = P + b * 65536;
    int l = threadIdx.x & 63, w = threadIdx.x >> 6;
    int wm = (w >> 1) * 32, wn = (w & 1) * 32;
#pragma unroll
    for (int mi = 0; mi < 2; ++mi)
#pragma unroll
        for (int ni = 0; ni < 2; ++ni)
#pragma unroll
            for (int r = 0; r < 4; ++r)
                atomicAdd(&D[(j0 + wm + mi * 16 + (l >> 4) * 4 + r) * NC + c0 + wn + ni * 16 + (l & 15)],
                          acc[mi][ni][r]);
}

// out = emb @ P^T. grid (128 nt, 4 jt, 2 b). A and B split on the fly from fp32.
__global__ __launch_bounds__(256) void k_out(const float* __restrict__ emb, const float* __restrict__ P,
                                             float* __restrict__ out) {
    __shared__ ushort lds[16384];
    ushort* Ah = lds; ushort* Al = lds + 4096; ushort* Bh = lds + 8192; ushort* Bl = lds + 12288;
    int nt = blockIdx.x, jt = blockIdx.y, b = blockIdx.z;
    const float* E = emb + b * (NN * NC);
    const float* Pb = P + b * 65536;
    int w = threadIdx.x >> 6;
    int wm = (w >> 1) * 32, wn = (w & 1) * 32;
    f32x4 acc[2][2] = {{{0.f, 0.f, 0.f, 0.f}, {0.f, 0.f, 0.f, 0.f}},
                       {{0.f, 0.f, 0.f, 0.f}, {0.f, 0.f, 0.f, 0.f}}};
    for (int t = 0; t < 4; ++t) {
        stage64_f32(Ah, Al, E, nt * 64, t * 64, NC);
        stage64_f32(Bh, Bl, Pb, jt * 64, t * 64, NC);
        __syncthreads();
        mfma_tile(Ah, Al, Bh, Bl, wm, wn, acc);
        __syncthreads();
    }
    ep_f32(out + b * (NN * NC), NC, nt * 64, jt * 64, acc);
}

// ---------------------------------------------------------------------------

extern "C" void kernel_launch(void* const* d_in, const int* in_sizes, int n_in,
                              void* d_out, int out_size, void* d_ws, size_t ws_size,
                              hipStream_t stream) {
    const float* emb = (const float*)d_in[0];
    const float* Wq  = (const float*)d_in[1];
    const float* Wk  = (const float*)d_in[2];
    const float* Wv  = (const float*)d_in[3];
    const float* Wo  = (const float*)d_in[4];
    float* out = (float*)d_out;
    float* ws  = (float*)d_ws;

    float* Gp    = ws;                 // [2][32][10][4096]
    float* attn  = ws;                 // alias (Gp dead after k_s2)
    float* P     = ws + 2621440;       // [2][256][256] fp32
    float* stats = ws + 2752512;       // 64 floats
    ushort* us   = (ushort*)(ws + 2752576);

    k_prep<<<dim3(512, 6),     dim3(256), 0, stream>>>(Wq, Wk, Wv, Wo, emb, us, P, stats);
    k_gram<<<dim3(10, 32, NB), dim3(256), 0, stream>>>(us, Gp);
    k_s2  <<<dim3(10, NB),     dim3(256), 0, stream>>>(Gp, us);
    k_t1  <<<dim3(32, 4, NB),  dim3(256), 0, stream>>>(us);
    k_attn<<<dim3(16, 16),     dim3(256), 0, stream>>>(us, attn, stats);
    k_sm  <<<dim3(16, 16),     dim3(256), 0, stream>>>(attn, stats, us);
    k_m   <<<dim3(16, 16),     dim3(256), 0, stream>>>(us);
    k_pt  <<<dim3(16, 16),     dim3(256), 0, stream>>>(us, P);
    k_out <<<dim3(128, 4, NB), dim3(256), 0, stream>>>(emb, P, out);
}